// Round 11
// baseline (227.167 us; speedup 1.0000x reference)
//
#include <hip/hip_runtime.h>
#include <hip/hip_bf16.h>
#include <stdint.h>

#define IC 32
#define OC 32
#define HID 32

// Angle binning: per node, PBIN u64 cells of (count << TSH | sum of t*2^20).
#define PBIN 16
#define TSH 44
#define TSCALE 1048576.0f   // 2^20

// Edge piecewise path: W(t) = M_c + t*K_c per linear piece c.
#define PBE 12
#define MAXN 65536          // g_cells/g_bkt capacity (nodes)
#define MAXE (1 << 20)      // overflow-list capacity (edges)
#define BKTD 8              // bucket depth (slots per node)

typedef __attribute__((ext_vector_type(8))) _Float16 half8;
typedef __attribute__((ext_vector_type(4))) float f32x4;
typedef unsigned long long u64;

static __device__ __forceinline__ _Float16 f2h(float f) { return (_Float16)f; }

// ---------------------------------------------------------------------------
// Device-global scratch (module-load allocated; rewritten in-stream).
// ---------------------------------------------------------------------------
__device__ __align__(16) _Float16 g_MK[PBE * 2 * 32 * 32];
__device__ float g_ekn[16];
__device__ float g_akn[16];
__device__ int   g_npc[2];                                   // [0]=edge, [1]=angle
__device__ __align__(16) u64 g_cells[(size_t)MAXN * PBIN];   // 8 MB
__device__ __align__(16) u64 g_bkt[(size_t)MAXN * BKTD];     // 4 MB (t,col)
__device__ __align__(16) unsigned g_cnt[MAXN];               // per-dst degree
__device__ __align__(16) unsigned g_ovf[MAXE];               // overflow edge ids
__device__ unsigned g_ovfn;

// ---------------------------------------------------------------------------
// L1: setup (knots + edge piece matrices, blocks < 48) fused with zeroing of
// out, the cell region, and the bucket counters (all blocks, grid-stride).
//   M_c = eb2 + sum_k on(k,c) b1k eW2k,  K_c = sum_k on(k,c) w1k eW2k
// ---------------------------------------------------------------------------
__global__ __launch_bounds__(512) void setup_zero(
    const float* __restrict__ eW1, const float* __restrict__ eb1,
    const float* __restrict__ eW2, const float* __restrict__ eb2,
    const float* __restrict__ aW1, const float* __restrict__ ab1,
    float* __restrict__ out, int outF4, int cellF4, int cntF4)
{
    __shared__ float ts_s[32];
    __shared__ int   rk_s[32];
    __shared__ int   re_s[32];
    const int tid = threadIdx.x;
    const int bid = blockIdx.x;

    if (bid == 0 && tid == 0) g_ovfn = 0u;

    if (bid < 48) {
        if (bid == 0 && tid < 16) { g_ekn[tid] = 1e30f; g_akn[tid] = 1e30f; }
        if (tid < 32) {   // edge-MLP hinge table (all 48 blocks need it)
            const int k = tid;
            const float w = eW1[k], b = eb1[k];
            const float ts = -b / w;
            const bool re = (w != 0.f) && (ts > 0.f) && (ts < 1.f);
            int rk = 0;
            for (int k2 = 0; k2 < 32; ++k2) {
                const float w2 = eW1[k2], b2 = eb1[k2];
                const float t2 = -b2 / w2;
                const bool re2 = (w2 != 0.f) && (t2 > 0.f) && (t2 < 1.f);
                rk += (re2 && (t2 < ts || (t2 == ts && k2 < k))) ? 1 : 0;
            }
            ts_s[k] = ts; rk_s[k] = rk; re_s[k] = re ? 1 : 0;
        }
        __syncthreads();

        if (bid == 0) {
            if (tid < 32) {
                if (re_s[tid]) g_ekn[rk_s[tid]] = ts_s[tid];
                if (tid == 0) {
                    int n = 0;
                    for (int k = 0; k < 32; ++k) n += re_s[k];
                    g_npc[0] = n + 1;
                }
            } else if (tid < 64) {   // angle-MLP knots
                const int k = tid - 32;
                const float w = aW1[k], b = ab1[k];
                const float ts = -b / w;
                const bool re = (w != 0.f) && (ts > 0.f) && (ts < 1.f);
                int rk = 0, nre = 0;
                for (int k2 = 0; k2 < 32; ++k2) {
                    const float w2 = aW1[k2], b2 = ab1[k2];
                    const float t2 = -b2 / w2;
                    const bool re2 = (w2 != 0.f) && (t2 > 0.f) && (t2 < 1.f);
                    nre += re2 ? 1 : 0;
                    rk += (re2 && (t2 < ts || (t2 == ts && k2 < k))) ? 1 : 0;
                }
                if (re) g_akn[rk] = ts;
                if (k == 0) g_npc[1] = nre + 1;
            }
        }

        const int gid = bid * 512 + tid;   // piece-matrix entries
        if (gid < PBE * 2 * 32 * 32) {
            const int i   = gid & 31;
            const int o   = (gid >> 5) & 31;
            const int mat = (gid >> 10) & 1;
            const int cc  = gid >> 11;
            float acc = (mat == 0) ? eb2[i * 32 + o] : 0.f;
            for (int k = 0; k < 32; ++k) {
                const bool flip = re_s[k] && (rk_s[k] < cc);
                const float w = eW1[k], b = eb1[k];
                const bool on0 = b > 0.f;
                const bool on = (w > 0.f) ? (on0 || flip) : (on0 && !flip);
                if (on) acc = fmaf((mat == 0 ? b : w),
                                   eW2[k * 1024 + i * 32 + o], acc);
            }
            g_MK[((cc * 2 + mat) * 32 + o) * 32 + i] = (_Float16)acc;
        }
    }

    // ---- zero out + cells + bucket counters (all blocks) ----
    const int total = outF4 + cellF4 + cntF4;
    const float4 z4 = make_float4(0.f, 0.f, 0.f, 0.f);
    for (int i = bid * 512 + tid; i < total; i += gridDim.x * 512) {
        if (i < outF4)               ((float4*)out)[i] = z4;
        else if (i < outF4 + cellF4) ((float4*)g_cells)[i - outF4] = z4;
        else                         ((float4*)g_cnt)[i - outF4 - cellF4] = z4;
    }
}

// ---------------------------------------------------------------------------
// L2: bin angles (1 u64 atomic each) + build edge dst-buckets (doBuild):
// per edge pos = atomicAdd(cnt[dst]); pos < BKTD -> slot (t,col), else
// overflow edge-id list (processed exactly by the mega overflow role).
// ---------------------------------------------------------------------------
__global__ __launch_bounds__(256) void angle_scatter(
    const float* __restrict__ angles, const int* __restrict__ angle_index,
    const float* __restrict__ edge_attr, const int* __restrict__ edge_index,
    u64* __restrict__ cells, int A, int E, int doBuild)
{
    u64* cp = cells ? cells : g_cells;
    float kn[16];
#pragma unroll
    for (int j = 0; j < 16; ++j) kn[j] = g_akn[j];

    const int i0 = blockIdx.x * blockDim.x + threadIdx.x;
    const int stride = gridDim.x * blockDim.x;

    for (int a = i0; a < A; a += stride) {
        const float t = angles[a];
        const int j = angle_index[A + a];   // center node
        int cc = 0;
#pragma unroll
        for (int jj = 0; jj < 16; ++jj) cc += (t >= kn[jj]) ? 1 : 0;
        if ((unsigned)cc < (unsigned)PBIN) {
            const u64 enc = ((u64)1 << TSH) | (u64)(unsigned)(t * TSCALE);
            atomicAdd(cp + (size_t)j * PBIN + cc, enc);
        }
    }

    if (doBuild) {
        for (int e = i0; e < E; e += stride) {
            const float t  = edge_attr[e];
            const int dst  = edge_index[e];
            const int col  = edge_index[E + e];
            const unsigned pos = atomicAdd(&g_cnt[dst], 1u);
            if (pos < BKTD) {
                g_bkt[(size_t)dst * BKTD + pos] =
                    ((u64)__float_as_uint(t) << 32) | (unsigned)col;
            } else {
                const unsigned oi = atomicAdd(&g_ovfn, 1u);
                if (oi < MAXE) g_ovf[oi] = (unsigned)e;
            }
        }
    }
}

// ---------------------------------------------------------------------------
// Gather body (proven R6-R9): per wave 16 nodes; lane (l15,q) builds
// g[k] = sum_c n_c*relu(tb_c*w1k+b1k); two mfma_f32_16x16x32_f16 -> 32 ch.
// ---------------------------------------------------------------------------
static __device__ __forceinline__ void angle_gather_wave(
    const u64* __restrict__ cells, float* __restrict__ out,
    const float* __restrict__ aW1, const float* __restrict__ ab1,
    const float* __restrict__ aW2, const float* __restrict__ ab2,
    int N, int base, int lane, bool addmode)
{
    const int q = lane >> 4, l15 = lane & 15;
    float w1s[8], b1s[8];
    int c0 = 0, c1 = 0;
#pragma unroll
    for (int k = 0; k < HID; ++k) {
        const float w = aW1[k], b = ab1[k];
        const bool pos = w > 0.f;
        const bool f0 = pos ? (b > 0.f) : !(b > 0.f);
        const bool f1 = pos ? ((w + b) > 0.f) : !((w + b) > 0.f);
        c0 += f0 ? 1 : 0;
        c1 += f1 ? 1 : 0;
        if ((k >> 3) == q) { w1s[k & 7] = w; b1s[k & 7] = b; }
    }
    int npc = c1 - c0 + 1;
    if (npc > PBIN) npc = PBIN;

    half8 Bf0, Bf1;
#pragma unroll
    for (int j = 0; j < 8; ++j) {
        Bf0[j] = f2h(aW2[(q * 8 + j) * OC + l15]);
        Bf1[j] = f2h(aW2[(q * 8 + j) * OC + 16 + l15]);
    }
    const float bias0 = ab2[l15];
    const float bias1 = ab2[16 + l15];

    const int jn = base + l15;
    const bool vn = (jn < N);
    const u64* cj = cells + (size_t)(vn ? jn : 0) * PBIN;
    float g[8] = {0.f, 0.f, 0.f, 0.f, 0.f, 0.f, 0.f, 0.f};
    float tot = 0.f;
    for (int cc = 0; cc < npc; ++cc) {
        const u64 v = vn ? cj[cc] : 0;
        if (v) {
            const float n  = (float)(unsigned)(v >> TSH);
            const float ts = (float)(v & (((u64)1 << TSH) - 1)) * (1.f / TSCALE);
            const float tb = ts / n;
#pragma unroll
            for (int k = 0; k < 8; ++k) {
                float h = fmaf(tb, w1s[k], b1s[k]);
                h = h > 0.f ? h : 0.f;
                g[k] = fmaf(n, h, g[k]);
            }
            tot += n;
        }
    }
    half8 a;
#pragma unroll
    for (int k = 0; k < 8; ++k) a[k] = f2h(g[k]);

    f32x4 acc0 = {0.f, 0.f, 0.f, 0.f};
    f32x4 acc1 = {0.f, 0.f, 0.f, 0.f};
    acc0 = __builtin_amdgcn_mfma_f32_16x16x32_f16(a, Bf0, acc0, 0, 0, 0);
    acc1 = __builtin_amdgcn_mfma_f32_16x16x32_f16(a, Bf1, acc1, 0, 0, 0);

#pragma unroll
    for (int r = 0; r < 4; ++r) {
        const int node = base + q * 4 + r;
        const float tr = __shfl(tot, q * 4 + r, 64);
        if (node < N) {
            const float v0 = fmaf(tr, bias0, acc0[r]);
            const float v1 = fmaf(tr, bias1, acc1[r]);
            if (addmode) {
                unsafeAtomicAdd(out + (size_t)node * OC + l15, v0);
                unsafeAtomicAdd(out + (size_t)node * OC + 16 + l15, v1);
            } else {
                out[(size_t)node * OC + l15]      = v0;
                out[(size_t)node * OC + 16 + l15] = v1;
            }
        }
    }
}

// Fallback standalone gather (N > MAXN): cells in out, overwrite mode.
__global__ __launch_bounds__(256) void angle_gather_ow(
    float* __restrict__ out,
    const float* __restrict__ aW1, const float* __restrict__ ab1,
    const float* __restrict__ aW2, const float* __restrict__ ab2, int N)
{
    const int lane = threadIdx.x & 63;
    const int wib  = threadIdx.x >> 6;
    const int base = (blockIdx.x * 4 + wib) * 16;
    if (base >= N) return;
    angle_gather_wave((const u64*)out, out, aW1, ab1, aW2, ab2,
                      N, base, lane, false);
}

// ---------------------------------------------------------------------------
// L3: mega kernel -- additive block roles:
//   [0,EB):   edge. Bucket mode: tiles of 16 SLOTS (= 2 nodes x 8-deep
//             bucket); a lane's 4 D-rows are always ONE node -> in-register
//             row sum + shfl_xor(16) q-merge -> 1 atomic/node/channel
//             (6.4M -> ~1.6M edge atomics). Non-bucket: R8 per-edge path.
//   [..+GB):  angle gather (atomicAdd)    [..+FA): angle fixup
//   [..+FE):  edge fixup (cc >= PBE)      [..+OV): bucket-overflow edges
// LDS piece matrices at the PROVEN 80B-stride layout (R9's 64B rows were an
// 8-way bank conflict: 16*l15 mod 32 hits only banks {0,16}).
// ---------------------------------------------------------------------------
__global__ __launch_bounds__(512, 4) void mega_kernel(
    const float* __restrict__ x, const int* __restrict__ edge_index,
    const float* __restrict__ edge_attr,
    const float* __restrict__ eW1, const float* __restrict__ eb1,
    const float* __restrict__ eW2, const float* __restrict__ eb2,
    const float* __restrict__ angles, const int* __restrict__ angle_index,
    const float* __restrict__ aW1, const float* __restrict__ ab1,
    const float* __restrict__ aW2, const float* __restrict__ ab2,
    float* __restrict__ out, int E, int A, int N,
    int EB, int GB, int FA, int FE, int useBkt)
{
    // [cc][mat][o(32)][i(40 f16, 32 used)] : 80B rows, 61.4 KB (R8-proven)
    __shared__ __align__(16) _Float16 B[PBE * 2 * 32 * 40];
    __shared__ float knl[16];

    const int tid = threadIdx.x;
    const int bid = blockIdx.x;

    if (bid < EB) {
        // ================= edge role =================
        for (int r = tid; r < PBE * 2 * 32; r += 512) {
            const float4* s = (const float4*)(g_MK + r * 32);
            float4 a0 = s[0], a1 = s[1], a2 = s[2], a3 = s[3];
            float4* d = (float4*)(B + r * 40);
            d[0] = a0; d[1] = a1; d[2] = a2; d[3] = a3;
        }
        if (tid < 16) knl[tid] = g_ekn[tid];
        __syncthreads();

        float kn[PBE];
#pragma unroll
        for (int j = 0; j < PBE; ++j) kn[j] = knl[j];
        int npc = g_npc[0];
        if (npc > PBE) npc = PBE;

        const int lane  = tid & 63;
        const int w8    = tid >> 6;
        const int gwave = bid * 8 + w8;
        const int ot    = gwave & 1;
        const int tile0 = gwave >> 1;
        const int tstride = (EB * 8) >> 1;
        const int q     = lane >> 4;
        const int l15   = lane & 15;
        const int ocol  = ot * 16 + l15;
        const _Float16* Bb = B + (size_t)ocol * 40 + q * 8;
        const half8 z = {0, 0, 0, 0, 0, 0, 0, 0};

        if (useBkt) {
            const int numST = (N + 1) >> 1;   // 16-slot tiles = 2 nodes
            for (int tile = tile0; tile < numST; tile += 2 * tstride) {
                const int tA = tile;
                const int tB = tile + tstride;
                const bool hasB = (tB < numST);

                // ---- tile A slots ----
                const int slotA = (tA << 4) + l15;
                const int nodeA = slotA >> 3;
                const unsigned cAn = (nodeA < N) ? g_cnt[nodeA] : 0u;
                const bool va = (unsigned)(l15 & 7) < (cAn < BKTD ? cAn : BKTD);
                const u64 pkA = va ? g_bkt[slotA] : 0ull;
                const float ta = __uint_as_float((unsigned)(pkA >> 32));
                const int colA = (int)(unsigned)(pkA & 0xffffffffu);

                // ---- tile B slots ----
                const int slotB = (tB << 4) + l15;
                const int nodeB = slotB >> 3;
                const unsigned cBn = (hasB && nodeB < N) ? g_cnt[nodeB] : 0u;
                const bool vb = (unsigned)(l15 & 7) < (cBn < BKTD ? cBn : BKTD);
                const u64 pkB = vb ? g_bkt[slotB] : 0ull;
                const float tb = __uint_as_float((unsigned)(pkB >> 32));
                const int colB = (int)(unsigned)(pkB & 0xffffffffu);

                const float* xpA = x + (size_t)colA * IC + q * 8;
                const float4 xloA = *(const float4*)(xpA);
                const float4 xhiA = *(const float4*)(xpA + 4);
                const float* xpB = x + (size_t)colB * IC + q * 8;
                const float4 xloB = *(const float4*)(xpB);
                const float4 xhiB = *(const float4*)(xpB + 4);

                int ccA = 0, ccB = 0;
#pragma unroll
                for (int j = 0; j < PBE; ++j) {
                    ccA += (ta >= kn[j]) ? 1 : 0;
                    ccB += (tb >= kn[j]) ? 1 : 0;
                }
                if (!va) ccA = -1;
                if (!vb) ccB = -1;

                half8 xhA, xhB;
                xhA[0] = f2h(xloA.x); xhA[1] = f2h(xloA.y);
                xhA[2] = f2h(xloA.z); xhA[3] = f2h(xloA.w);
                xhA[4] = f2h(xhiA.x); xhA[5] = f2h(xhiA.y);
                xhA[6] = f2h(xhiA.z); xhA[7] = f2h(xhiA.w);
                xhB[0] = f2h(xloB.x); xhB[1] = f2h(xloB.y);
                xhB[2] = f2h(xloB.z); xhB[3] = f2h(xloB.w);
                xhB[4] = f2h(xhiB.x); xhB[5] = f2h(xhiB.y);
                xhB[6] = f2h(xhiB.z); xhB[7] = f2h(xhiB.w);

                const _Float16 thA = f2h(ta), thB = f2h(tb);
                const half8 tvA = {thA, thA, thA, thA, thA, thA, thA, thA};
                const half8 tvB = {thB, thB, thB, thB, thB, thB, thB, thB};
                const half8 xtA = xhA * tvA;
                const half8 xtB = xhB * tvB;

                f32x4 accA = {0.f, 0.f, 0.f, 0.f};
                f32x4 accB = {0.f, 0.f, 0.f, 0.f};
                for (int c = 0; c < npc; ++c) {
                    const half8 bM = *(const half8*)(Bb + (size_t)(c * 2 + 0) * 32 * 40);
                    const half8 bK = *(const half8*)(Bb + (size_t)(c * 2 + 1) * 32 * 40);
                    const half8 aA1 = (ccA == c) ? xhA : z;
                    const half8 aA2 = (ccA == c) ? xtA : z;
                    const half8 aB1 = (ccB == c) ? xhB : z;
                    const half8 aB2 = (ccB == c) ? xtB : z;
                    accA = __builtin_amdgcn_mfma_f32_16x16x32_f16(aA1, bM, accA, 0, 0, 0);
                    accB = __builtin_amdgcn_mfma_f32_16x16x32_f16(aB1, bM, accB, 0, 0, 0);
                    accA = __builtin_amdgcn_mfma_f32_16x16x32_f16(aA2, bK, accA, 0, 0, 0);
                    accB = __builtin_amdgcn_mfma_f32_16x16x32_f16(aB2, bK, accB, 0, 0, 0);
                }

                // rows q*4+r -> slots tA*16+q*4+r -> node 2tA + (q>>1):
                // sum 4 rows in-register, merge q-pair via shfl_xor(16),
                // single atomic per node per channel.
                float sA = accA[0] + accA[1] + accA[2] + accA[3];
                float sB = accB[0] + accB[1] + accB[2] + accB[3];
                sA += __shfl_xor(sA, 16, 64);
                sB += __shfl_xor(sB, 16, 64);
                if (!(q & 1)) {
                    const int nA = (tA << 1) + (q >> 1);
                    if (nA < N && g_cnt[nA] > 0u)
                        unsafeAtomicAdd(out + (size_t)nA * OC + ocol, sA);
                    if (hasB) {
                        const int nB = (tB << 1) + (q >> 1);
                        if (nB < N && g_cnt[nB] > 0u)
                            unsafeAtomicAdd(out + (size_t)nB * OC + ocol, sB);
                    }
                }
            }
        } else {
            // -------- fallback: R8 per-edge tiles, 4 dst-atomics/lane -------
            const int numTiles = (E + 15) >> 4;
            for (int tile = tile0; tile < numTiles; tile += 2 * tstride) {
                const int tA = tile;
                const int tB = tile + tstride;
                const bool hasB = (tB < numTiles);

                const int eA  = (tA << 4) + l15;
                const bool va = (eA < E);
                const float ta = va ? edge_attr[eA] : 0.f;
                const int colA = va ? edge_index[E + eA] : 0;

                const int eB  = (tB << 4) + l15;
                const bool vb = hasB && (eB < E);
                const float tb = vb ? edge_attr[eB] : 0.f;
                const int colB = vb ? edge_index[E + eB] : 0;

                const float* xpA = x + (size_t)colA * IC + q * 8;
                const float4 xloA = *(const float4*)(xpA);
                const float4 xhiA = *(const float4*)(xpA + 4);
                const float* xpB = x + (size_t)colB * IC + q * 8;
                const float4 xloB = *(const float4*)(xpB);
                const float4 xhiB = *(const float4*)(xpB + 4);

                int dstsA[4], dstsB[4];
                const int ebaseA = (tA << 4) + q * 4;
                const int ebaseB = (tB << 4) + q * 4;
#pragma unroll
                for (int r = 0; r < 4; ++r) {
                    const int erA = ebaseA + r;
                    dstsA[r] = (erA < E) ? edge_index[erA] : -1;
                    const int erB = ebaseB + r;
                    dstsB[r] = (hasB && erB < E) ? edge_index[erB] : -1;
                }

                int ccA = 0, ccB = 0;
#pragma unroll
                for (int j = 0; j < PBE; ++j) {
                    ccA += (ta >= kn[j]) ? 1 : 0;
                    ccB += (tb >= kn[j]) ? 1 : 0;
                }

                half8 xhA, xhB;
                xhA[0] = f2h(xloA.x); xhA[1] = f2h(xloA.y);
                xhA[2] = f2h(xloA.z); xhA[3] = f2h(xloA.w);
                xhA[4] = f2h(xhiA.x); xhA[5] = f2h(xhiA.y);
                xhA[6] = f2h(xhiA.z); xhA[7] = f2h(xhiA.w);
                xhB[0] = f2h(xloB.x); xhB[1] = f2h(xloB.y);
                xhB[2] = f2h(xloB.z); xhB[3] = f2h(xloB.w);
                xhB[4] = f2h(xhiB.x); xhB[5] = f2h(xhiB.y);
                xhB[6] = f2h(xhiB.z); xhB[7] = f2h(xhiB.w);

                const _Float16 thA = f2h(ta), thB = f2h(tb);
                const half8 tvA = {thA, thA, thA, thA, thA, thA, thA, thA};
                const half8 tvB = {thB, thB, thB, thB, thB, thB, thB, thB};
                const half8 xtA = xhA * tvA;
                const half8 xtB = xhB * tvB;

                f32x4 accA = {0.f, 0.f, 0.f, 0.f};
                f32x4 accB = {0.f, 0.f, 0.f, 0.f};
                for (int c = 0; c < npc; ++c) {
                    const half8 bM = *(const half8*)(Bb + (size_t)(c * 2 + 0) * 32 * 40);
                    const half8 bK = *(const half8*)(Bb + (size_t)(c * 2 + 1) * 32 * 40);
                    const half8 aA1 = (ccA == c) ? xhA : z;
                    const half8 aA2 = (ccA == c) ? xtA : z;
                    const half8 aB1 = (ccB == c) ? xhB : z;
                    const half8 aB2 = (ccB == c) ? xtB : z;
                    accA = __builtin_amdgcn_mfma_f32_16x16x32_f16(aA1, bM, accA, 0, 0, 0);
                    accB = __builtin_amdgcn_mfma_f32_16x16x32_f16(aB1, bM, accB, 0, 0, 0);
                    accA = __builtin_amdgcn_mfma_f32_16x16x32_f16(aA2, bK, accA, 0, 0, 0);
                    accB = __builtin_amdgcn_mfma_f32_16x16x32_f16(aB2, bK, accB, 0, 0, 0);
                }

#pragma unroll
                for (int r = 0; r < 4; ++r) {
                    if (dstsA[r] >= 0)
                        unsafeAtomicAdd(out + (size_t)dstsA[r] * OC + ocol, accA[r]);
                }
#pragma unroll
                for (int r = 0; r < 4; ++r) {
                    if (dstsB[r] >= 0)
                        unsafeAtomicAdd(out + (size_t)dstsB[r] * OC + ocol, accB[r]);
                }
            }
        }
    } else if (bid < EB + GB) {
        // ================= angle gather role (atomicAdd) ====================
        const int lane = tid & 63;
        const int wib  = tid >> 6;
        const int base = ((bid - EB) * 8 + wib) * 16;
        if (base < N)
            angle_gather_wave(g_cells, out, aW1, ab1, aW2, ab2,
                              N, base, lane, true);
    } else if (bid < EB + GB + FA) {
        // ================= angle fixup role (cc >= PBIN) ====================
        if (g_npc[1] <= PBIN) return;
        const float kn15 = g_akn[15];
        float w1[HID], b1[HID];
#pragma unroll
        for (int k = 0; k < HID; ++k) { w1[k] = aW1[k]; b1[k] = ab1[k]; }
        int i0 = (bid - EB - GB) * 512 + tid;
        int stride = FA * 512;
        for (int a = i0; a < A; a += stride) {
            const float t = angles[a];
            if (t < kn15) continue;
            const int j = angle_index[A + a];
            float h[HID];
#pragma unroll
            for (int k = 0; k < HID; ++k) {
                float v = fmaf(t, w1[k], b1[k]);
                h[k] = v > 0.f ? v : 0.f;
            }
            for (int o = 0; o < OC; ++o) {
                float s = ab2[o];
#pragma unroll
                for (int k = 0; k < HID; ++k) s = fmaf(h[k], aW2[k * OC + o], s);
                unsafeAtomicAdd(out + (size_t)j * OC + o, s);
            }
        }
    } else if (bid < EB + GB + FA + FE) {
        // ================= edge fixup role (cc >= PBE) ======================
        if (g_npc[0] <= PBE) return;
        const float knb = g_ekn[PBE - 1];
        int i0 = (bid - EB - GB - FA) * 512 + tid;
        int stride = FE * 512;
        for (int e = i0; e < E; e += stride) {
            const float t = edge_attr[e];
            if (t < knb) continue;
            const int col = edge_index[E + e];
            const int dst = edge_index[e];
            float h[HID];
#pragma unroll
            for (int k = 0; k < HID; ++k) {
                float v = fmaf(t, eW1[k], eb1[k]);
                h[k] = v > 0.f ? v : 0.f;
            }
            for (int o = 0; o < OC; ++o) {
                float s = 0.f;
                for (int i = 0; i < IC; ++i) {
                    float wio = eb2[i * 32 + o];
#pragma unroll
                    for (int k = 0; k < HID; ++k)
                        wio = fmaf(h[k], eW2[k * 1024 + i * 32 + o], wio);
                    s = fmaf(x[(size_t)col * IC + i], wio, s);
                }
                unsafeAtomicAdd(out + (size_t)dst * OC + o, s);
            }
        }
    } else {
        // ================= bucket-overflow role (pos >= BKTD) ===============
        unsigned nov = g_ovfn;
        if (nov > MAXE) nov = MAXE;
        float kn[PBE];
#pragma unroll
        for (int j = 0; j < PBE; ++j) kn[j] = g_ekn[j];
        const int OVB = 32;
        int i0 = (bid - EB - GB - FA - FE) * 512 + tid;
        int stride = OVB * 512;
        for (unsigned i = (unsigned)i0; i < nov; i += stride) {
            const int e = (int)g_ovf[i];
            const float t = edge_attr[e];
            int cc = 0;
#pragma unroll
            for (int j = 0; j < PBE; ++j) cc += (t >= kn[j]) ? 1 : 0;
            if (cc >= PBE) continue;   // covered by edge fixup
            const int col = edge_index[E + e];
            const int dst = edge_index[e];
            float xv[IC];
#pragma unroll
            for (int i2 = 0; i2 < IC; ++i2) xv[i2] = x[(size_t)col * IC + i2];
            for (int o = 0; o < OC; ++o) {
                const _Float16* mr = g_MK + ((size_t)(cc * 2 + 0) * 32 + o) * 32;
                const _Float16* kr = g_MK + ((size_t)(cc * 2 + 1) * 32 + o) * 32;
                float s = 0.f;
#pragma unroll
                for (int i2 = 0; i2 < IC; ++i2)
                    s = fmaf(fmaf(t, (float)kr[i2], (float)mr[i2]), xv[i2], s);
                unsafeAtomicAdd(out + (size_t)dst * OC + o, s);
            }
        }
    }
}

// ---------------------------------------------------------------------------
extern "C" void kernel_launch(void* const* d_in, const int* in_sizes, int n_in,
                              void* d_out, int out_size, void* d_ws, size_t ws_size,
                              hipStream_t stream)
{
    const float* x          = (const float*)d_in[0];
    const int*   edge_index = (const int*)d_in[1];
    const float* edge_attr  = (const float*)d_in[2];
    const int*   angle_index= (const int*)d_in[3];
    const float* angles     = (const float*)d_in[4];
    const float* eW1        = (const float*)d_in[5];
    const float* eb1        = (const float*)d_in[6];
    const float* eW2        = (const float*)d_in[7];
    const float* eb2        = (const float*)d_in[8];
    const float* aW1        = (const float*)d_in[9];
    const float* ab1        = (const float*)d_in[10];
    const float* aW2        = (const float*)d_in[11];
    const float* ab2        = (const float*)d_in[12];
    float* out = (float*)d_out;
    (void)d_ws; (void)ws_size;

    const int E = in_sizes[1] / 2;
    const int A = in_sizes[3] / 3;
    const int N = in_sizes[0] / IC;

    const int outF4 = out_size / 4;
    const int sblocks = (A + 255) / 256;
    const bool fast = (N <= MAXN) && (E <= MAXE);

    if (fast) {
        const int cellF4 = N * 8;           // N*16 u64 -> float4 count
        const int cntF4  = (N + 3) / 4;     // N u32 -> float4 count
        int zg = (outF4 + cellF4 + cntF4 + 511) / 512;
        if (zg < 48) zg = 48;
        setup_zero<<<zg, 512, 0, stream>>>(eW1, eb1, eW2, eb2, aW1, ab1,
                                           out, outF4, cellF4, cntF4);

        angle_scatter<<<sblocks, 256, 0, stream>>>(angles, angle_index,
                                                   edge_attr, edge_index,
                                                   nullptr, A, E, 1);

        const int EB = 512;
        const int GB = (N + 127) / 128;
        const int FA = 64, FE = 64, OV = 32;
        mega_kernel<<<EB + GB + FA + FE + OV, 512, 0, stream>>>(
            x, edge_index, edge_attr, eW1, eb1, eW2, eb2,
            angles, angle_index, aW1, ab1, aW2, ab2,
            out, E, A, N, EB, GB, FA, FE, 1);
    } else {
        int zg = (outF4 + 511) / 512;
        if (zg < 48) zg = 48;
        setup_zero<<<zg, 512, 0, stream>>>(eW1, eb1, eW2, eb2, aW1, ab1,
                                           out, outF4, 0, 0);
        angle_scatter<<<sblocks, 256, 0, stream>>>(angles, angle_index,
                                                   edge_attr, edge_index,
                                                   (u64*)out, A, E, 0);
        angle_gather_ow<<<(N + 63) / 64, 256, 0, stream>>>(out, aW1, ab1,
                                                           aW2, ab2, N);
        const int EB = 512, FA = 64, FE = 64;
        mega_kernel<<<EB + FA + FE, 512, 0, stream>>>(
            x, edge_index, edge_attr, eW1, eb1, eW2, eb2,
            angles, angle_index, aW1, ab1, aW2, ab2,
            out, E, A, N, EB, 0, FA, FE, 0);
    }
}

// Round 12
// 165.062 us; speedup vs baseline: 1.3763x; 1.3763x over previous
//
#include <hip/hip_runtime.h>
#include <hip/hip_bf16.h>
#include <stdint.h>

#define IC 32
#define OC 32
#define HID 32

// Angle binning: per node, PBIN u64 cells of (count << TSH | sum of t*2^20).
#define PBIN 16
#define TSH 44
#define TSCALE 1048576.0f   // 2^20

// Edge piecewise path: W(t) = M_c + t*K_c per linear piece c.
#define PBE 12
#define MAXN 65536          // g_cells capacity (nodes); N larger -> fallback

typedef __attribute__((ext_vector_type(8))) _Float16 half8;
typedef __attribute__((ext_vector_type(4))) float f32x4;
typedef unsigned long long u64;

static __device__ __forceinline__ _Float16 f2h(float f) { return (_Float16)f; }

// ---------------------------------------------------------------------------
// Device-global scratch (module-load allocated; rewritten in-stream).
// ---------------------------------------------------------------------------
__device__ __align__(16) _Float16 g_MK[PBE * 2 * 32 * 32];
__device__ float g_ekn[16];
__device__ float g_akn[16];
__device__ int   g_npc[2];   // [0]=edge pieces, [1]=angle pieces
__device__ __align__(16) u64 g_cells[(size_t)MAXN * PBIN];   // 8 MB

// ---------------------------------------------------------------------------
// L1: setup (knots + edge piece matrices, blocks < 48) fused with zeroing of
// out and the used cell region (all blocks, grid-stride float4).
//   M_c = eb2 + sum_k on(k,c) b1k eW2k,  K_c = sum_k on(k,c) w1k eW2k
// ---------------------------------------------------------------------------
__global__ __launch_bounds__(512) void setup_zero(
    const float* __restrict__ eW1, const float* __restrict__ eb1,
    const float* __restrict__ eW2, const float* __restrict__ eb2,
    const float* __restrict__ aW1, const float* __restrict__ ab1,
    float* __restrict__ out, int outF4, int cellF4)
{
    __shared__ float ts_s[32];
    __shared__ int   rk_s[32];
    __shared__ int   re_s[32];
    const int tid = threadIdx.x;
    const int bid = blockIdx.x;

    if (bid < 48) {
        if (bid == 0 && tid < 16) { g_ekn[tid] = 1e30f; g_akn[tid] = 1e30f; }
        if (tid < 32) {   // edge-MLP hinge table (all 48 blocks need it)
            const int k = tid;
            const float w = eW1[k], b = eb1[k];
            const float ts = -b / w;
            const bool re = (w != 0.f) && (ts > 0.f) && (ts < 1.f);
            int rk = 0;
            for (int k2 = 0; k2 < 32; ++k2) {
                const float w2 = eW1[k2], b2 = eb1[k2];
                const float t2 = -b2 / w2;
                const bool re2 = (w2 != 0.f) && (t2 > 0.f) && (t2 < 1.f);
                rk += (re2 && (t2 < ts || (t2 == ts && k2 < k))) ? 1 : 0;
            }
            ts_s[k] = ts; rk_s[k] = rk; re_s[k] = re ? 1 : 0;
        }
        __syncthreads();

        if (bid == 0) {
            if (tid < 32) {
                if (re_s[tid]) g_ekn[rk_s[tid]] = ts_s[tid];
                if (tid == 0) {
                    int n = 0;
                    for (int k = 0; k < 32; ++k) n += re_s[k];
                    g_npc[0] = n + 1;
                }
            } else if (tid < 64) {   // angle-MLP knots
                const int k = tid - 32;
                const float w = aW1[k], b = ab1[k];
                const float ts = -b / w;
                const bool re = (w != 0.f) && (ts > 0.f) && (ts < 1.f);
                int rk = 0, nre = 0;
                for (int k2 = 0; k2 < 32; ++k2) {
                    const float w2 = aW1[k2], b2 = ab1[k2];
                    const float t2 = -b2 / w2;
                    const bool re2 = (w2 != 0.f) && (t2 > 0.f) && (t2 < 1.f);
                    nre += re2 ? 1 : 0;
                    rk += (re2 && (t2 < ts || (t2 == ts && k2 < k))) ? 1 : 0;
                }
                if (re) g_akn[rk] = ts;
                if (k == 0) g_npc[1] = nre + 1;
            }
        }

        const int gid = bid * 512 + tid;   // piece-matrix entries
        if (gid < PBE * 2 * 32 * 32) {
            const int i   = gid & 31;
            const int o   = (gid >> 5) & 31;
            const int mat = (gid >> 10) & 1;
            const int cc  = gid >> 11;
            float acc = (mat == 0) ? eb2[i * 32 + o] : 0.f;
            for (int k = 0; k < 32; ++k) {
                const bool flip = re_s[k] && (rk_s[k] < cc);
                const float w = eW1[k], b = eb1[k];
                const bool on0 = b > 0.f;
                const bool on = (w > 0.f) ? (on0 || flip) : (on0 && !flip);
                if (on) acc = fmaf((mat == 0 ? b : w),
                                   eW2[k * 1024 + i * 32 + o], acc);
            }
            g_MK[((cc * 2 + mat) * 32 + o) * 32 + i] = (_Float16)acc;
        }
    }

    // ---- zero out + used cells (all blocks) ----
    const int total = outF4 + cellF4;
    const float4 z4 = make_float4(0.f, 0.f, 0.f, 0.f);
    for (int i = bid * 512 + tid; i < total; i += gridDim.x * 512) {
        if (i < outF4) ((float4*)out)[i] = z4;
        else           ((float4*)g_cells)[i - outF4] = z4;
    }
}

// ---------------------------------------------------------------------------
// L2: bin angles. cc = #realized knots <= t; one u64 atomic per angle.
// ---------------------------------------------------------------------------
__global__ __launch_bounds__(256) void angle_scatter(
    const float* __restrict__ angles, const int* __restrict__ angle_index,
    u64* __restrict__ cells, int A)
{
    u64* cp = cells ? cells : g_cells;
    float kn[16];
#pragma unroll
    for (int j = 0; j < 16; ++j) kn[j] = g_akn[j];

    int i0 = blockIdx.x * blockDim.x + threadIdx.x;
    int stride = gridDim.x * blockDim.x;
    for (int a = i0; a < A; a += stride) {
        const float t = angles[a];
        const int j = angle_index[A + a];   // center node
        int cc = 0;
#pragma unroll
        for (int jj = 0; jj < 16; ++jj) cc += (t >= kn[jj]) ? 1 : 0;
        if ((unsigned)cc < (unsigned)PBIN) {
            const u64 enc = ((u64)1 << TSH) | (u64)(unsigned)(t * TSCALE);
            atomicAdd(cp + (size_t)j * PBIN + cc, enc);
        }
    }
}

// ---------------------------------------------------------------------------
// Gather body (proven R6-R11): per wave 16 nodes; lane (l15,q) builds
// g[k] = sum_c n_c*relu(tb_c*w1k+b1k); two mfma_f32_16x16x32_f16 -> 32 ch.
// ---------------------------------------------------------------------------
static __device__ __forceinline__ void angle_gather_wave(
    const u64* __restrict__ cells, float* __restrict__ out,
    const float* __restrict__ aW1, const float* __restrict__ ab1,
    const float* __restrict__ aW2, const float* __restrict__ ab2,
    int N, int base, int lane, bool addmode)
{
    const int q = lane >> 4, l15 = lane & 15;
    float w1s[8], b1s[8];
    int c0 = 0, c1 = 0;
#pragma unroll
    for (int k = 0; k < HID; ++k) {
        const float w = aW1[k], b = ab1[k];
        const bool pos = w > 0.f;
        const bool f0 = pos ? (b > 0.f) : !(b > 0.f);
        const bool f1 = pos ? ((w + b) > 0.f) : !((w + b) > 0.f);
        c0 += f0 ? 1 : 0;
        c1 += f1 ? 1 : 0;
        if ((k >> 3) == q) { w1s[k & 7] = w; b1s[k & 7] = b; }
    }
    int npc = c1 - c0 + 1;
    if (npc > PBIN) npc = PBIN;

    half8 Bf0, Bf1;
#pragma unroll
    for (int j = 0; j < 8; ++j) {
        Bf0[j] = f2h(aW2[(q * 8 + j) * OC + l15]);
        Bf1[j] = f2h(aW2[(q * 8 + j) * OC + 16 + l15]);
    }
    const float bias0 = ab2[l15];
    const float bias1 = ab2[16 + l15];

    const int jn = base + l15;
    const bool vn = (jn < N);
    const u64* cj = cells + (size_t)(vn ? jn : 0) * PBIN;
    float g[8] = {0.f, 0.f, 0.f, 0.f, 0.f, 0.f, 0.f, 0.f};
    float tot = 0.f;
    for (int cc = 0; cc < npc; ++cc) {
        const u64 v = vn ? cj[cc] : 0;
        if (v) {
            const float n  = (float)(unsigned)(v >> TSH);
            const float ts = (float)(v & (((u64)1 << TSH) - 1)) * (1.f / TSCALE);
            const float tb = ts / n;
#pragma unroll
            for (int k = 0; k < 8; ++k) {
                float h = fmaf(tb, w1s[k], b1s[k]);
                h = h > 0.f ? h : 0.f;
                g[k] = fmaf(n, h, g[k]);
            }
            tot += n;
        }
    }
    half8 a;
#pragma unroll
    for (int k = 0; k < 8; ++k) a[k] = f2h(g[k]);

    f32x4 acc0 = {0.f, 0.f, 0.f, 0.f};
    f32x4 acc1 = {0.f, 0.f, 0.f, 0.f};
    acc0 = __builtin_amdgcn_mfma_f32_16x16x32_f16(a, Bf0, acc0, 0, 0, 0);
    acc1 = __builtin_amdgcn_mfma_f32_16x16x32_f16(a, Bf1, acc1, 0, 0, 0);

#pragma unroll
    for (int r = 0; r < 4; ++r) {
        const int node = base + q * 4 + r;
        const float tr = __shfl(tot, q * 4 + r, 64);
        if (node < N) {
            const float v0 = fmaf(tr, bias0, acc0[r]);
            const float v1 = fmaf(tr, bias1, acc1[r]);
            if (addmode) {
                unsafeAtomicAdd(out + (size_t)node * OC + l15, v0);
                unsafeAtomicAdd(out + (size_t)node * OC + 16 + l15, v1);
            } else {
                out[(size_t)node * OC + l15]      = v0;
                out[(size_t)node * OC + 16 + l15] = v1;
            }
        }
    }
}

// Fallback standalone gather (N > MAXN): cells in out, overwrite mode.
__global__ __launch_bounds__(256) void angle_gather_ow(
    float* __restrict__ out,
    const float* __restrict__ aW1, const float* __restrict__ ab1,
    const float* __restrict__ aW2, const float* __restrict__ ab2, int N)
{
    const int lane = threadIdx.x & 63;
    const int wib  = threadIdx.x >> 6;
    const int base = (blockIdx.x * 4 + wib) * 16;
    if (base >= N) return;
    angle_gather_wave((const u64*)out, out, aW1, ab1, aW2, ab2,
                      N, base, lane, false);
}

// ---------------------------------------------------------------------------
// L3: mega kernel -- additive block roles (R8 structure, new LDS layout):
//   [0,EB):   edge (per-edge tiles, piecewise W(t), K=64 MFMA)
//   [..+GB):  angle gather (atomicAdd)    [..+FA): angle fixup
//   [..+FE):  edge fixup (cc >= PBE)
// LDS: 24 matrices x 32 rows x 64B with XOR swizzle
//   float4_idx = (row*4 + chunk) ^ (row&7)
// -> 48 KB (was 61.4 KB padded) => 3 blocks/CU, 24 waves/CU (1.5x R8).
// Read side: laneF4 = (ocol*4+q) ^ (ocol&7) is piece-invariant (piece
// stride = mult of 32 rows => row&7 == ocol&7); 16 lanes/quad spread over
// 8 distinct 16B slots x2 = 2-way = free (m136). This is the CLEAN
// occupancy experiment R9 botched (its 64B rows had an 8-way conflict).
// ---------------------------------------------------------------------------
__global__ __launch_bounds__(512, 6) void mega_kernel(
    const float* __restrict__ x, const int* __restrict__ edge_index,
    const float* __restrict__ edge_attr,
    const float* __restrict__ eW1, const float* __restrict__ eb1,
    const float* __restrict__ eW2, const float* __restrict__ eb2,
    const float* __restrict__ angles, const int* __restrict__ angle_index,
    const float* __restrict__ aW1, const float* __restrict__ ab1,
    const float* __restrict__ aW2, const float* __restrict__ ab2,
    float* __restrict__ out, int E, int A, int N,
    int EB, int GB, int FA, int FE)
{
    __shared__ __align__(16) _Float16 B[PBE * 2 * 32 * 32];   // 48 KB
    __shared__ float knl[16];

    const int tid = threadIdx.x;
    const int bid = blockIdx.x;

    if (bid < EB) {
        // ================= edge role (8 waves) =================
        // stage with XOR swizzle: src float4 idx = row*4+ch, dst = idx^(row&7)
        for (int idx = tid; idx < PBE * 2 * 32 * 4; idx += 512) {
            const int r = idx >> 2;
            ((float4*)B)[idx ^ (r & 7)] = ((const float4*)g_MK)[idx];
        }
        if (tid < 16) knl[tid] = g_ekn[tid];
        __syncthreads();

        float kn[PBE];
#pragma unroll
        for (int j = 0; j < PBE; ++j) kn[j] = knl[j];
        int npc = g_npc[0];
        if (npc > PBE) npc = PBE;

        const int lane  = tid & 63;
        const int w8    = tid >> 6;
        const int gwave = bid * 8 + w8;
        const int ot    = gwave & 1;
        const int tile0 = gwave >> 1;
        const int tstride = (EB * 8) >> 1;
        const int q     = lane >> 4;
        const int l15   = lane & 15;
        const int ocol  = ot * 16 + l15;
        // lane's swizzled base; piece step is +1024 f16 per matrix
        const int laneF4 = (ocol * 4 + q) ^ (ocol & 7);
        const _Float16* Bb = B + laneF4 * 8;
        const half8 z = {0, 0, 0, 0, 0, 0, 0, 0};

        const int numTiles = (E + 15) >> 4;

        for (int tile = tile0; tile < numTiles; tile += 2 * tstride) {
            const int tA = tile;
            const int tB = tile + tstride;
            const bool hasB = (tB < numTiles);

            const int eA  = (tA << 4) + l15;
            const bool va = (eA < E);
            const float ta = va ? edge_attr[eA] : 0.f;
            const int colA = va ? edge_index[E + eA] : 0;

            const int eB  = (tB << 4) + l15;
            const bool vb = hasB && (eB < E);
            const float tb = vb ? edge_attr[eB] : 0.f;
            const int colB = vb ? edge_index[E + eB] : 0;

            const float* xpA = x + (size_t)colA * IC + q * 8;
            const float4 xloA = *(const float4*)(xpA);
            const float4 xhiA = *(const float4*)(xpA + 4);
            const float* xpB = x + (size_t)colB * IC + q * 8;
            const float4 xloB = *(const float4*)(xpB);
            const float4 xhiB = *(const float4*)(xpB + 4);

            int dstsA[4], dstsB[4];
            const int ebaseA = (tA << 4) + q * 4;
            const int ebaseB = (tB << 4) + q * 4;
#pragma unroll
            for (int r = 0; r < 4; ++r) {
                const int erA = ebaseA + r;
                dstsA[r] = (erA < E) ? edge_index[erA] : -1;
                const int erB = ebaseB + r;
                dstsB[r] = (hasB && erB < E) ? edge_index[erB] : -1;
            }

            int ccA = 0, ccB = 0;
#pragma unroll
            for (int j = 0; j < PBE; ++j) {
                ccA += (ta >= kn[j]) ? 1 : 0;
                ccB += (tb >= kn[j]) ? 1 : 0;
            }

            half8 xhA, xhB;
            xhA[0] = f2h(xloA.x); xhA[1] = f2h(xloA.y);
            xhA[2] = f2h(xloA.z); xhA[3] = f2h(xloA.w);
            xhA[4] = f2h(xhiA.x); xhA[5] = f2h(xhiA.y);
            xhA[6] = f2h(xhiA.z); xhA[7] = f2h(xhiA.w);
            xhB[0] = f2h(xloB.x); xhB[1] = f2h(xloB.y);
            xhB[2] = f2h(xloB.z); xhB[3] = f2h(xloB.w);
            xhB[4] = f2h(xhiB.x); xhB[5] = f2h(xhiB.y);
            xhB[6] = f2h(xhiB.z); xhB[7] = f2h(xhiB.w);

            const _Float16 thA = f2h(ta), thB = f2h(tb);
            const half8 tvA = {thA, thA, thA, thA, thA, thA, thA, thA};
            const half8 tvB = {thB, thB, thB, thB, thB, thB, thB, thB};
            const half8 xtA = xhA * tvA;
            const half8 xtB = xhB * tvB;

            f32x4 accA = {0.f, 0.f, 0.f, 0.f};
            f32x4 accB = {0.f, 0.f, 0.f, 0.f};
            for (int c = 0; c < npc; ++c) {
                const half8 bM = *(const half8*)(Bb + (size_t)(c * 2 + 0) * 1024);
                const half8 bK = *(const half8*)(Bb + (size_t)(c * 2 + 1) * 1024);
                const half8 aA1 = (ccA == c) ? xhA : z;
                const half8 aA2 = (ccA == c) ? xtA : z;
                const half8 aB1 = (ccB == c) ? xhB : z;
                const half8 aB2 = (ccB == c) ? xtB : z;
                accA = __builtin_amdgcn_mfma_f32_16x16x32_f16(aA1, bM, accA, 0, 0, 0);
                accB = __builtin_amdgcn_mfma_f32_16x16x32_f16(aB1, bM, accB, 0, 0, 0);
                accA = __builtin_amdgcn_mfma_f32_16x16x32_f16(aA2, bK, accA, 0, 0, 0);
                accB = __builtin_amdgcn_mfma_f32_16x16x32_f16(aB2, bK, accB, 0, 0, 0);
            }

#pragma unroll
            for (int r = 0; r < 4; ++r) {
                if (dstsA[r] >= 0)
                    unsafeAtomicAdd(out + (size_t)dstsA[r] * OC + ocol, accA[r]);
            }
#pragma unroll
            for (int r = 0; r < 4; ++r) {
                if (dstsB[r] >= 0)
                    unsafeAtomicAdd(out + (size_t)dstsB[r] * OC + ocol, accB[r]);
            }
        }
    } else if (bid < EB + GB) {
        // ================= angle gather role (atomicAdd) ====================
        const int lane = tid & 63;
        const int wib  = tid >> 6;
        const int base = ((bid - EB) * 8 + wib) * 16;
        if (base < N)
            angle_gather_wave(g_cells, out, aW1, ab1, aW2, ab2,
                              N, base, lane, true);
    } else if (bid < EB + GB + FA) {
        // ================= angle fixup role (cc >= PBIN) ====================
        if (g_npc[1] <= PBIN) return;
        const float kn15 = g_akn[15];
        float w1[HID], b1[HID];
#pragma unroll
        for (int k = 0; k < HID; ++k) { w1[k] = aW1[k]; b1[k] = ab1[k]; }
        int i0 = (bid - EB - GB) * 512 + tid;
        int stride = FA * 512;
        for (int a = i0; a < A; a += stride) {
            const float t = angles[a];
            if (t < kn15) continue;
            const int j = angle_index[A + a];
            float h[HID];
#pragma unroll
            for (int k = 0; k < HID; ++k) {
                float v = fmaf(t, w1[k], b1[k]);
                h[k] = v > 0.f ? v : 0.f;
            }
            for (int o = 0; o < OC; ++o) {
                float s = ab2[o];
#pragma unroll
                for (int k = 0; k < HID; ++k) s = fmaf(h[k], aW2[k * OC + o], s);
                unsafeAtomicAdd(out + (size_t)j * OC + o, s);
            }
        }
    } else {
        // ================= edge fixup role (cc >= PBE) ======================
        if (g_npc[0] <= PBE) return;
        const float knb = g_ekn[PBE - 1];
        int i0 = (bid - EB - GB - FA) * 512 + tid;
        int stride = FE * 512;
        for (int e = i0; e < E; e += stride) {
            const float t = edge_attr[e];
            if (t < knb) continue;
            const int col = edge_index[E + e];
            const int dst = edge_index[e];
            float h[HID];
#pragma unroll
            for (int k = 0; k < HID; ++k) {
                float v = fmaf(t, eW1[k], eb1[k]);
                h[k] = v > 0.f ? v : 0.f;
            }
            for (int o = 0; o < OC; ++o) {
                float s = 0.f;
                for (int i = 0; i < IC; ++i) {
                    float wio = eb2[i * 32 + o];
#pragma unroll
                    for (int k = 0; k < HID; ++k)
                        wio = fmaf(h[k], eW2[k * 1024 + i * 32 + o], wio);
                    s = fmaf(x[(size_t)col * IC + i], wio, s);
                }
                unsafeAtomicAdd(out + (size_t)dst * OC + o, s);
            }
        }
    }
}

// ---------------------------------------------------------------------------
extern "C" void kernel_launch(void* const* d_in, const int* in_sizes, int n_in,
                              void* d_out, int out_size, void* d_ws, size_t ws_size,
                              hipStream_t stream)
{
    const float* x          = (const float*)d_in[0];
    const int*   edge_index = (const int*)d_in[1];
    const float* edge_attr  = (const float*)d_in[2];
    const int*   angle_index= (const int*)d_in[3];
    const float* angles     = (const float*)d_in[4];
    const float* eW1        = (const float*)d_in[5];
    const float* eb1        = (const float*)d_in[6];
    const float* eW2        = (const float*)d_in[7];
    const float* eb2        = (const float*)d_in[8];
    const float* aW1        = (const float*)d_in[9];
    const float* ab1        = (const float*)d_in[10];
    const float* aW2        = (const float*)d_in[11];
    const float* ab2        = (const float*)d_in[12];
    float* out = (float*)d_out;
    (void)d_ws; (void)ws_size;

    const int E = in_sizes[1] / 2;
    const int A = in_sizes[3] / 3;
    const int N = in_sizes[0] / IC;

    const int outF4 = out_size / 4;
    const int sblocks = (A + 255) / 256;

    if (N <= MAXN) {
        // ---- fast path: 3 launches ----
        const int cellF4 = N * 8;     // N*16 u64 = N*8 float4
        int zg = (outF4 + cellF4 + 511) / 512;
        if (zg < 48) zg = 48;
        setup_zero<<<zg, 512, 0, stream>>>(eW1, eb1, eW2, eb2, aW1, ab1,
                                           out, outF4, cellF4);

        angle_scatter<<<sblocks, 256, 0, stream>>>(angles, angle_index,
                                                   nullptr, A);

        const int EB = 768;   // 3 blocks/CU at 48 KB LDS
        const int GB = (N + 127) / 128;
        const int FA = 64, FE = 64;
        mega_kernel<<<EB + GB + FA + FE, 512, 0, stream>>>(
            x, edge_index, edge_attr, eW1, eb1, eW2, eb2,
            angles, angle_index, aW1, ab1, aW2, ab2,
            out, E, A, N, EB, GB, FA, FE);
    } else {
        // ---- fallback (N > MAXN): cells in out, gather overwrites ----
        int zg = (outF4 + 511) / 512;
        if (zg < 48) zg = 48;
        setup_zero<<<zg, 512, 0, stream>>>(eW1, eb1, eW2, eb2, aW1, ab1,
                                           out, outF4, 0);
        angle_scatter<<<sblocks, 256, 0, stream>>>(angles, angle_index,
                                                   (u64*)out, A);
        angle_gather_ow<<<(N + 63) / 64, 256, 0, stream>>>(out, aW1, ab1,
                                                           aW2, ab2, N);
        const int EB = 768, FA = 64, FE = 64;
        mega_kernel<<<EB + FA + FE, 512, 0, stream>>>(
            x, edge_index, edge_attr, eW1, eb1, eW2, eb2,
            angles, angle_index, aW1, ab1, aW2, ab2,
            out, E, A, N, EB, 0, FA, FE);
    }
}

// Round 13
// 157.136 us; speedup vs baseline: 1.4457x; 1.0504x over previous
//
#include <hip/hip_runtime.h>
#include <hip/hip_bf16.h>
#include <stdint.h>

#define IC 32
#define OC 32
#define HID 32

// Angle binning: per node, PBIN u64 cells of (count << TSH | sum of t*2^20).
#define PBIN 16
#define TSH 44
#define TSCALE 1048576.0f   // 2^20

// Edge piecewise path: W(t) = M_c + t*K_c per linear piece c.
#define PBE 12
#define MAXN 65536          // g_cells capacity (nodes); N larger -> fallback

typedef __attribute__((ext_vector_type(8))) _Float16 half8;
typedef __attribute__((ext_vector_type(4))) float f32x4;
typedef unsigned long long u64;

static __device__ __forceinline__ _Float16 f2h(float f) { return (_Float16)f; }

// ---------------------------------------------------------------------------
// Device-global scratch (module-load allocated; rewritten in-stream).
// ---------------------------------------------------------------------------
__device__ __align__(16) _Float16 g_MK[PBE * 2 * 32 * 32];
__device__ float g_ekn[16];
__device__ float g_akn[16];
__device__ int   g_npc[2];   // [0]=edge pieces, [1]=angle pieces
__device__ __align__(16) u64 g_cells[(size_t)MAXN * PBIN];   // 8 MB

// ---------------------------------------------------------------------------
// L1: setup (knots + edge piece matrices, blocks < 48) fused with zeroing of
// out and the used cell region (all blocks, grid-stride float4).
//   M_c = eb2 + sum_k on(k,c) b1k eW2k,  K_c = sum_k on(k,c) w1k eW2k
// ---------------------------------------------------------------------------
__global__ __launch_bounds__(512) void setup_zero(
    const float* __restrict__ eW1, const float* __restrict__ eb1,
    const float* __restrict__ eW2, const float* __restrict__ eb2,
    const float* __restrict__ aW1, const float* __restrict__ ab1,
    float* __restrict__ out, int outF4, int cellF4)
{
    __shared__ float ts_s[32];
    __shared__ int   rk_s[32];
    __shared__ int   re_s[32];
    const int tid = threadIdx.x;
    const int bid = blockIdx.x;

    if (bid < 48) {
        if (bid == 0 && tid < 16) { g_ekn[tid] = 1e30f; g_akn[tid] = 1e30f; }
        if (tid < 32) {   // edge-MLP hinge table (all 48 blocks need it)
            const int k = tid;
            const float w = eW1[k], b = eb1[k];
            const float ts = -b / w;
            const bool re = (w != 0.f) && (ts > 0.f) && (ts < 1.f);
            int rk = 0;
            for (int k2 = 0; k2 < 32; ++k2) {
                const float w2 = eW1[k2], b2 = eb1[k2];
                const float t2 = -b2 / w2;
                const bool re2 = (w2 != 0.f) && (t2 > 0.f) && (t2 < 1.f);
                rk += (re2 && (t2 < ts || (t2 == ts && k2 < k))) ? 1 : 0;
            }
            ts_s[k] = ts; rk_s[k] = rk; re_s[k] = re ? 1 : 0;
        }
        __syncthreads();

        if (bid == 0) {
            if (tid < 32) {
                if (re_s[tid]) g_ekn[rk_s[tid]] = ts_s[tid];
                if (tid == 0) {
                    int n = 0;
                    for (int k = 0; k < 32; ++k) n += re_s[k];
                    g_npc[0] = n + 1;
                }
            } else if (tid < 64) {   // angle-MLP knots
                const int k = tid - 32;
                const float w = aW1[k], b = ab1[k];
                const float ts = -b / w;
                const bool re = (w != 0.f) && (ts > 0.f) && (ts < 1.f);
                int rk = 0, nre = 0;
                for (int k2 = 0; k2 < 32; ++k2) {
                    const float w2 = aW1[k2], b2 = ab1[k2];
                    const float t2 = -b2 / w2;
                    const bool re2 = (w2 != 0.f) && (t2 > 0.f) && (t2 < 1.f);
                    nre += re2 ? 1 : 0;
                    rk += (re2 && (t2 < ts || (t2 == ts && k2 < k))) ? 1 : 0;
                }
                if (re) g_akn[rk] = ts;
                if (k == 0) g_npc[1] = nre + 1;
            }
        }

        const int gid = bid * 512 + tid;   // piece-matrix entries
        if (gid < PBE * 2 * 32 * 32) {
            const int i   = gid & 31;
            const int o   = (gid >> 5) & 31;
            const int mat = (gid >> 10) & 1;
            const int cc  = gid >> 11;
            float acc = (mat == 0) ? eb2[i * 32 + o] : 0.f;
            for (int k = 0; k < 32; ++k) {
                const bool flip = re_s[k] && (rk_s[k] < cc);
                const float w = eW1[k], b = eb1[k];
                const bool on0 = b > 0.f;
                const bool on = (w > 0.f) ? (on0 || flip) : (on0 && !flip);
                if (on) acc = fmaf((mat == 0 ? b : w),
                                   eW2[k * 1024 + i * 32 + o], acc);
            }
            g_MK[((cc * 2 + mat) * 32 + o) * 32 + i] = (_Float16)acc;
        }
    }

    // ---- zero out + used cells (all blocks) ----
    const int total = outF4 + cellF4;
    const float4 z4 = make_float4(0.f, 0.f, 0.f, 0.f);
    for (int i = bid * 512 + tid; i < total; i += gridDim.x * 512) {
        if (i < outF4) ((float4*)out)[i] = z4;
        else           ((float4*)g_cells)[i - outF4] = z4;
    }
}

// ---------------------------------------------------------------------------
// L2: bin angles. cc = #realized knots <= t; one u64 atomic per angle.
// ---------------------------------------------------------------------------
__global__ __launch_bounds__(256) void angle_scatter(
    const float* __restrict__ angles, const int* __restrict__ angle_index,
    u64* __restrict__ cells, int A)
{
    u64* cp = cells ? cells : g_cells;
    float kn[16];
#pragma unroll
    for (int j = 0; j < 16; ++j) kn[j] = g_akn[j];

    int i0 = blockIdx.x * blockDim.x + threadIdx.x;
    int stride = gridDim.x * blockDim.x;
    for (int a = i0; a < A; a += stride) {
        const float t = angles[a];
        const int j = angle_index[A + a];   // center node
        int cc = 0;
#pragma unroll
        for (int jj = 0; jj < 16; ++jj) cc += (t >= kn[jj]) ? 1 : 0;
        if ((unsigned)cc < (unsigned)PBIN) {
            const u64 enc = ((u64)1 << TSH) | (u64)(unsigned)(t * TSCALE);
            atomicAdd(cp + (size_t)j * PBIN + cc, enc);
        }
    }
}

// ---------------------------------------------------------------------------
// Gather body (proven R6-R12): per wave 16 nodes; lane (l15,q) builds
// g[k] = sum_c n_c*relu(tb_c*w1k+b1k); two mfma_f32_16x16x32_f16 -> 32 ch.
// ---------------------------------------------------------------------------
static __device__ __forceinline__ void angle_gather_wave(
    const u64* __restrict__ cells, float* __restrict__ out,
    const float* __restrict__ aW1, const float* __restrict__ ab1,
    const float* __restrict__ aW2, const float* __restrict__ ab2,
    int N, int base, int lane, bool addmode)
{
    const int q = lane >> 4, l15 = lane & 15;
    float w1s[8], b1s[8];
    int c0 = 0, c1 = 0;
#pragma unroll
    for (int k = 0; k < HID; ++k) {
        const float w = aW1[k], b = ab1[k];
        const bool pos = w > 0.f;
        const bool f0 = pos ? (b > 0.f) : !(b > 0.f);
        const bool f1 = pos ? ((w + b) > 0.f) : !((w + b) > 0.f);
        c0 += f0 ? 1 : 0;
        c1 += f1 ? 1 : 0;
        if ((k >> 3) == q) { w1s[k & 7] = w; b1s[k & 7] = b; }
    }
    int npc = c1 - c0 + 1;
    if (npc > PBIN) npc = PBIN;

    half8 Bf0, Bf1;
#pragma unroll
    for (int j = 0; j < 8; ++j) {
        Bf0[j] = f2h(aW2[(q * 8 + j) * OC + l15]);
        Bf1[j] = f2h(aW2[(q * 8 + j) * OC + 16 + l15]);
    }
    const float bias0 = ab2[l15];
    const float bias1 = ab2[16 + l15];

    const int jn = base + l15;
    const bool vn = (jn < N);
    const u64* cj = cells + (size_t)(vn ? jn : 0) * PBIN;
    float g[8] = {0.f, 0.f, 0.f, 0.f, 0.f, 0.f, 0.f, 0.f};
    float tot = 0.f;
    for (int cc = 0; cc < npc; ++cc) {
        const u64 v = vn ? cj[cc] : 0;
        if (v) {
            const float n  = (float)(unsigned)(v >> TSH);
            const float ts = (float)(v & (((u64)1 << TSH) - 1)) * (1.f / TSCALE);
            const float tb = ts / n;
#pragma unroll
            for (int k = 0; k < 8; ++k) {
                float h = fmaf(tb, w1s[k], b1s[k]);
                h = h > 0.f ? h : 0.f;
                g[k] = fmaf(n, h, g[k]);
            }
            tot += n;
        }
    }
    half8 a;
#pragma unroll
    for (int k = 0; k < 8; ++k) a[k] = f2h(g[k]);

    f32x4 acc0 = {0.f, 0.f, 0.f, 0.f};
    f32x4 acc1 = {0.f, 0.f, 0.f, 0.f};
    acc0 = __builtin_amdgcn_mfma_f32_16x16x32_f16(a, Bf0, acc0, 0, 0, 0);
    acc1 = __builtin_amdgcn_mfma_f32_16x16x32_f16(a, Bf1, acc1, 0, 0, 0);

#pragma unroll
    for (int r = 0; r < 4; ++r) {
        const int node = base + q * 4 + r;
        const float tr = __shfl(tot, q * 4 + r, 64);
        if (node < N) {
            const float v0 = fmaf(tr, bias0, acc0[r]);
            const float v1 = fmaf(tr, bias1, acc1[r]);
            if (addmode) {
                unsafeAtomicAdd(out + (size_t)node * OC + l15, v0);
                unsafeAtomicAdd(out + (size_t)node * OC + 16 + l15, v1);
            } else {
                out[(size_t)node * OC + l15]      = v0;
                out[(size_t)node * OC + 16 + l15] = v1;
            }
        }
    }
}

// Fallback standalone gather (N > MAXN): cells in out, overwrite mode.
__global__ __launch_bounds__(256) void angle_gather_ow(
    float* __restrict__ out,
    const float* __restrict__ aW1, const float* __restrict__ ab1,
    const float* __restrict__ aW2, const float* __restrict__ ab2, int N)
{
    const int lane = threadIdx.x & 63;
    const int wib  = threadIdx.x >> 6;
    const int base = (blockIdx.x * 4 + wib) * 16;
    if (base >= N) return;
    angle_gather_wave((const u64*)out, out, aW1, ab1, aW2, ab2,
                      N, base, lane, false);
}

// ---------------------------------------------------------------------------
// L3: mega kernel -- additive block roles (R8 structure, 48 KB swizzled LDS):
//   [0,EB):   edge (per-edge tiles, piecewise W(t), K=64 MFMA)
//   [..+GB):  angle gather (atomicAdd)    [..+FA): angle fixup
//   [..+FE):  edge fixup (cc >= PBE)
// LDS: 24 matrices x 32 rows x 64B, XOR swizzle f4idx = (row*4+ch)^(row&7)
// -> 48 KB, conflict-clean (R12: same 813K count as R8's padded layout).
// R13 = R12 with __launch_bounds__(512,4) instead of (512,6): R12's bound
// squeezed VGPR 60->40 and spilled to scratch (FETCH +9MB, WRITE +19MB).
// (512,4) restores natural ~60-VGPR alloc; LDS still allows 3 blocks/CU.
// This is the clean occupancy experiment (R9: bank-conflict confound;
// R12: spill confound).
// ---------------------------------------------------------------------------
__global__ __launch_bounds__(512, 4) void mega_kernel(
    const float* __restrict__ x, const int* __restrict__ edge_index,
    const float* __restrict__ edge_attr,
    const float* __restrict__ eW1, const float* __restrict__ eb1,
    const float* __restrict__ eW2, const float* __restrict__ eb2,
    const float* __restrict__ angles, const int* __restrict__ angle_index,
    const float* __restrict__ aW1, const float* __restrict__ ab1,
    const float* __restrict__ aW2, const float* __restrict__ ab2,
    float* __restrict__ out, int E, int A, int N,
    int EB, int GB, int FA, int FE)
{
    __shared__ __align__(16) _Float16 B[PBE * 2 * 32 * 32];   // 48 KB
    __shared__ float knl[16];

    const int tid = threadIdx.x;
    const int bid = blockIdx.x;

    if (bid < EB) {
        // ================= edge role (8 waves) =================
        // stage with XOR swizzle: src float4 idx = row*4+ch, dst = idx^(row&7)
        for (int idx = tid; idx < PBE * 2 * 32 * 4; idx += 512) {
            const int r = idx >> 2;
            ((float4*)B)[idx ^ (r & 7)] = ((const float4*)g_MK)[idx];
        }
        if (tid < 16) knl[tid] = g_ekn[tid];
        __syncthreads();

        float kn[PBE];
#pragma unroll
        for (int j = 0; j < PBE; ++j) kn[j] = knl[j];
        int npc = g_npc[0];
        if (npc > PBE) npc = PBE;

        const int lane  = tid & 63;
        const int w8    = tid >> 6;
        const int gwave = bid * 8 + w8;
        const int ot    = gwave & 1;
        const int tile0 = gwave >> 1;
        const int tstride = (EB * 8) >> 1;
        const int q     = lane >> 4;
        const int l15   = lane & 15;
        const int ocol  = ot * 16 + l15;
        // lane's swizzled base; piece step is +1024 f16 per matrix
        const int laneF4 = (ocol * 4 + q) ^ (ocol & 7);
        const _Float16* Bb = B + laneF4 * 8;
        const half8 z = {0, 0, 0, 0, 0, 0, 0, 0};

        const int numTiles = (E + 15) >> 4;

        for (int tile = tile0; tile < numTiles; tile += 2 * tstride) {
            const int tA = tile;
            const int tB = tile + tstride;
            const bool hasB = (tB < numTiles);

            const int eA  = (tA << 4) + l15;
            const bool va = (eA < E);
            const float ta = va ? edge_attr[eA] : 0.f;
            const int colA = va ? edge_index[E + eA] : 0;

            const int eB  = (tB << 4) + l15;
            const bool vb = hasB && (eB < E);
            const float tb = vb ? edge_attr[eB] : 0.f;
            const int colB = vb ? edge_index[E + eB] : 0;

            const float* xpA = x + (size_t)colA * IC + q * 8;
            const float4 xloA = *(const float4*)(xpA);
            const float4 xhiA = *(const float4*)(xpA + 4);
            const float* xpB = x + (size_t)colB * IC + q * 8;
            const float4 xloB = *(const float4*)(xpB);
            const float4 xhiB = *(const float4*)(xpB + 4);

            int dstsA[4], dstsB[4];
            const int ebaseA = (tA << 4) + q * 4;
            const int ebaseB = (tB << 4) + q * 4;
#pragma unroll
            for (int r = 0; r < 4; ++r) {
                const int erA = ebaseA + r;
                dstsA[r] = (erA < E) ? edge_index[erA] : -1;
                const int erB = ebaseB + r;
                dstsB[r] = (hasB && erB < E) ? edge_index[erB] : -1;
            }

            int ccA = 0, ccB = 0;
#pragma unroll
            for (int j = 0; j < PBE; ++j) {
                ccA += (ta >= kn[j]) ? 1 : 0;
                ccB += (tb >= kn[j]) ? 1 : 0;
            }

            half8 xhA, xhB;
            xhA[0] = f2h(xloA.x); xhA[1] = f2h(xloA.y);
            xhA[2] = f2h(xloA.z); xhA[3] = f2h(xloA.w);
            xhA[4] = f2h(xhiA.x); xhA[5] = f2h(xhiA.y);
            xhA[6] = f2h(xhiA.z); xhA[7] = f2h(xhiA.w);
            xhB[0] = f2h(xloB.x); xhB[1] = f2h(xloB.y);
            xhB[2] = f2h(xloB.z); xhB[3] = f2h(xloB.w);
            xhB[4] = f2h(xhiB.x); xhB[5] = f2h(xhiB.y);
            xhB[6] = f2h(xhiB.z); xhB[7] = f2h(xhiB.w);

            const _Float16 thA = f2h(ta), thB = f2h(tb);
            const half8 tvA = {thA, thA, thA, thA, thA, thA, thA, thA};
            const half8 tvB = {thB, thB, thB, thB, thB, thB, thB, thB};
            const half8 xtA = xhA * tvA;
            const half8 xtB = xhB * tvB;

            f32x4 accA = {0.f, 0.f, 0.f, 0.f};
            f32x4 accB = {0.f, 0.f, 0.f, 0.f};
            for (int c = 0; c < npc; ++c) {
                const half8 bM = *(const half8*)(Bb + (size_t)(c * 2 + 0) * 1024);
                const half8 bK = *(const half8*)(Bb + (size_t)(c * 2 + 1) * 1024);
                const half8 aA1 = (ccA == c) ? xhA : z;
                const half8 aA2 = (ccA == c) ? xtA : z;
                const half8 aB1 = (ccB == c) ? xhB : z;
                const half8 aB2 = (ccB == c) ? xtB : z;
                accA = __builtin_amdgcn_mfma_f32_16x16x32_f16(aA1, bM, accA, 0, 0, 0);
                accB = __builtin_amdgcn_mfma_f32_16x16x32_f16(aB1, bM, accB, 0, 0, 0);
                accA = __builtin_amdgcn_mfma_f32_16x16x32_f16(aA2, bK, accA, 0, 0, 0);
                accB = __builtin_amdgcn_mfma_f32_16x16x32_f16(aB2, bK, accB, 0, 0, 0);
            }

#pragma unroll
            for (int r = 0; r < 4; ++r) {
                if (dstsA[r] >= 0)
                    unsafeAtomicAdd(out + (size_t)dstsA[r] * OC + ocol, accA[r]);
            }
#pragma unroll
            for (int r = 0; r < 4; ++r) {
                if (dstsB[r] >= 0)
                    unsafeAtomicAdd(out + (size_t)dstsB[r] * OC + ocol, accB[r]);
            }
        }
    } else if (bid < EB + GB) {
        // ================= angle gather role (atomicAdd) ====================
        const int lane = tid & 63;
        const int wib  = tid >> 6;
        const int base = ((bid - EB) * 8 + wib) * 16;
        if (base < N)
            angle_gather_wave(g_cells, out, aW1, ab1, aW2, ab2,
                              N, base, lane, true);
    } else if (bid < EB + GB + FA) {
        // ================= angle fixup role (cc >= PBIN) ====================
        if (g_npc[1] <= PBIN) return;
        const float kn15 = g_akn[15];
        float w1[HID], b1[HID];
#pragma unroll
        for (int k = 0; k < HID; ++k) { w1[k] = aW1[k]; b1[k] = ab1[k]; }
        int i0 = (bid - EB - GB) * 512 + tid;
        int stride = FA * 512;
        for (int a = i0; a < A; a += stride) {
            const float t = angles[a];
            if (t < kn15) continue;
            const int j = angle_index[A + a];
            float h[HID];
#pragma unroll
            for (int k = 0; k < HID; ++k) {
                float v = fmaf(t, w1[k], b1[k]);
                h[k] = v > 0.f ? v : 0.f;
            }
            for (int o = 0; o < OC; ++o) {
                float s = ab2[o];
#pragma unroll
                for (int k = 0; k < HID; ++k) s = fmaf(h[k], aW2[k * OC + o], s);
                unsafeAtomicAdd(out + (size_t)j * OC + o, s);
            }
        }
    } else {
        // ================= edge fixup role (cc >= PBE) ======================
        if (g_npc[0] <= PBE) return;
        const float knb = g_ekn[PBE - 1];
        int i0 = (bid - EB - GB - FA) * 512 + tid;
        int stride = FE * 512;
        for (int e = i0; e < E; e += stride) {
            const float t = edge_attr[e];
            if (t < knb) continue;
            const int col = edge_index[E + e];
            const int dst = edge_index[e];
            float h[HID];
#pragma unroll
            for (int k = 0; k < HID; ++k) {
                float v = fmaf(t, eW1[k], eb1[k]);
                h[k] = v > 0.f ? v : 0.f;
            }
            for (int o = 0; o < OC; ++o) {
                float s = 0.f;
                for (int i = 0; i < IC; ++i) {
                    float wio = eb2[i * 32 + o];
#pragma unroll
                    for (int k = 0; k < HID; ++k)
                        wio = fmaf(h[k], eW2[k * 1024 + i * 32 + o], wio);
                    s = fmaf(x[(size_t)col * IC + i], wio, s);
                }
                unsafeAtomicAdd(out + (size_t)dst * OC + o, s);
            }
        }
    }
}

// ---------------------------------------------------------------------------
extern "C" void kernel_launch(void* const* d_in, const int* in_sizes, int n_in,
                              void* d_out, int out_size, void* d_ws, size_t ws_size,
                              hipStream_t stream)
{
    const float* x          = (const float*)d_in[0];
    const int*   edge_index = (const int*)d_in[1];
    const float* edge_attr  = (const float*)d_in[2];
    const int*   angle_index= (const int*)d_in[3];
    const float* angles     = (const float*)d_in[4];
    const float* eW1        = (const float*)d_in[5];
    const float* eb1        = (const float*)d_in[6];
    const float* eW2        = (const float*)d_in[7];
    const float* eb2        = (const float*)d_in[8];
    const float* aW1        = (const float*)d_in[9];
    const float* ab1        = (const float*)d_in[10];
    const float* aW2        = (const float*)d_in[11];
    const float* ab2        = (const float*)d_in[12];
    float* out = (float*)d_out;
    (void)d_ws; (void)ws_size;

    const int E = in_sizes[1] / 2;
    const int A = in_sizes[3] / 3;
    const int N = in_sizes[0] / IC;

    const int outF4 = out_size / 4;
    const int sblocks = (A + 255) / 256;

    if (N <= MAXN) {
        // ---- fast path: 3 launches ----
        const int cellF4 = N * 8;     // N*16 u64 = N*8 float4
        int zg = (outF4 + cellF4 + 511) / 512;
        if (zg < 48) zg = 48;
        setup_zero<<<zg, 512, 0, stream>>>(eW1, eb1, eW2, eb2, aW1, ab1,
                                           out, outF4, cellF4);

        angle_scatter<<<sblocks, 256, 0, stream>>>(angles, angle_index,
                                                   nullptr, A);

        const int EB = 768;   // 3 blocks/CU at 48 KB LDS (if VGPR allows)
        const int GB = (N + 127) / 128;
        const int FA = 64, FE = 64;
        mega_kernel<<<EB + GB + FA + FE, 512, 0, stream>>>(
            x, edge_index, edge_attr, eW1, eb1, eW2, eb2,
            angles, angle_index, aW1, ab1, aW2, ab2,
            out, E, A, N, EB, GB, FA, FE);
    } else {
        // ---- fallback (N > MAXN): cells in out, gather overwrites ----
        int zg = (outF4 + 511) / 512;
        if (zg < 48) zg = 48;
        setup_zero<<<zg, 512, 0, stream>>>(eW1, eb1, eW2, eb2, aW1, ab1,
                                           out, outF4, 0);
        angle_scatter<<<sblocks, 256, 0, stream>>>(angles, angle_index,
                                                   (u64*)out, A);
        angle_gather_ow<<<(N + 63) / 64, 256, 0, stream>>>(out, aW1, ab1,
                                                           aW2, ab2, N);
        const int EB = 768, FA = 64, FE = 64;
        mega_kernel<<<EB + FA + FE, 512, 0, stream>>>(
            x, edge_index, edge_attr, eW1, eb1, eW2, eb2,
            angles, angle_index, aW1, ab1, aW2, ab2,
            out, E, A, N, EB, 0, FA, FE);
    }
}